// Round 12
// baseline (42.245 us; speedup 1.0000x reference)
//
#include <hip/hip_runtime.h>

// Problem constants (match reference)
#define NB 8
#define NT 8
#define NO 25
#define NC 3
#define NH 192
#define NW 640
#define NP 16
#define ND 768
#define NGH 12
#define NGW 2
#define NKP (NB*NT*NO)   // 1600 keypoints
#define NK (NC*NP*NP)    // 768 (GEMM K)
#define NHALF (NKP*2)    // 3200 pool blocks: (keypoint, row-half), 3 channels each
#define NSTREAM 1536     // L3-warming streamer blocks (8 XCD x 192 parts)
#define NCVW ((NK*ND)/(256*4))  // 576 convw blocks (float4 per thread)

#define S_STRIDE 42      // shorts per row (even: u32-aligned writes/reads)
#define S_ROWS 97        // half-footprint rows <= 97
#define S_SLAB (S_ROWS * S_STRIDE)   // shorts per channel slab (4074, even)

typedef __attribute__((ext_vector_type(4))) float  f32x4;
typedef __attribute__((ext_vector_type(8))) short  bf16x8;

static __device__ __forceinline__ unsigned short f2bf(float f) {
  union { float f; unsigned u; } x; x.f = f;
  unsigned r = x.u + 0x7FFFu + ((x.u >> 16) & 1u);   // round-to-nearest-even
  return (unsigned short)(r >> 16);
}
static __device__ __forceinline__ unsigned packbf(float lo, float hi) {
  return (unsigned)f2bf(lo) | ((unsigned)f2bf(hi) << 16);
}
static __device__ __forceinline__ float bflo(unsigned u) {
  union { unsigned x; float f; } v; v.x = u << 16; return v.f;
}
static __device__ __forceinline__ float bfhi(unsigned u) {
  union { unsigned x; float f; } v; v.x = u & 0xFFFF0000u; return v.f;
}

// ---------------------------------------------------------------------------
// Kernel 1 (fused), three block roles in dispatch order:
//   [0, NSTREAM):                L3 warmers — stream features cols [160,640)
//                                (all sampled cols; cmin_al >= 172) linearly
//                                at streaming BW so the poolers' scattered
//                                gathers hit a warm L3 (half the fill latency,
//                                ~2x gather BW — the pool is line-fill bound).
//   [NSTREAM, NSTREAM+NCVW):     conv_w f32 -> bf16 convert.
//   [NSTREAM+NCVW, +NHALF):      ROI-align pooling, one block per
//                                (keypoint, row-half), all 3 channels,
//                                bf16 LDS slabs (24.5 KB -> 6 blocks/CU).
// ---------------------------------------------------------------------------
__global__ __launch_bounds__(256) void pool_convw_kernel(
    const float* __restrict__ features,   // [B][C][T][H][W] f32
    const float* __restrict__ keypoints,  // [N][3] (kx, ky, kr)
    const float* __restrict__ conv_w,     // [768][768] f32
    unsigned short* __restrict__ pooled,  // [N][768] bf16
    unsigned short* __restrict__ wbf)     // [768][768] bf16
{
  __shared__ unsigned short S[3 * S_SLAB + 16];   // 24,476 B; +16 guard

  const int bid = blockIdx.x;
  const int tid = threadIdx.x;

  if (bid < NSTREAM) {                    // ---- L3 warmer path ----
    // XCD x owns batch bb=x: planes [24x, 24(x+1)) are CONTIGUOUS in memory
    // ((bb*NC+ch)*NT+timg for bb=x spans exactly [24x, 24x+24)).
    // part = bid>>3 in [0,192): 8 parts per plane, 24 rows each.
    const int x     = bid & 7;
    const int part  = bid >> 3;
    const int plane = 24 * x + (part >> 3);
    const int row0  = (part & 7) * 24;
    const float* pb = features + (size_t)plane * (NH * NW) + (size_t)row0 * NW + 160;
    const int rr = tid >> 7;              // 0/1: two rows per iteration
    const int tt = tid & 127;             // lane within row (120 active)
#pragma unroll
    for (int it = 0; it < 12; ++it) {
      if (tt < 120) {
        const float4 v = reinterpret_cast<const float4*>(pb + (size_t)(it * 2 + rr) * NW)[tt];
        asm volatile("" :: "v"(v.x), "v"(v.y), "v"(v.z), "v"(v.w));  // keep load
      }
    }
    return;
  }

  if (bid < NSTREAM + NCVW) {             // ---- conv_w convert path ----
    const int i = (bid - NSTREAM) * 256 + tid;    // float4 index
    const float4 v = reinterpret_cast<const float4*>(conv_w)[i];
    ushort4 o;
    o.x = f2bf(v.x); o.y = f2bf(v.y); o.z = f2bf(v.z); o.w = f2bf(v.w);
    reinterpret_cast<ushort4*>(wbf)[i] = o;
    return;                               // no barrier on this path (block-uniform)
  }

  // ---- pooling path ----
  // XCD-chunked swizzle over 3200 (keypoint,half) blocks (3200 = 8*400).
  // NSTREAM+NCVW = 2112 = 264*8 keeps the blockIdx->XCD phase aligned.
  const int rb      = bid - NSTREAM - NCVW;
  const int logical = (rb & 7) * (NHALF / 8) + (rb >> 3);
  const int n       = logical >> 1;
  const int half    = logical & 1;        // 0: i-bins [0,8), 1: [8,16)

  const float kx = keypoints[n * 3 + 0];
  const float ky = keypoints[n * 3 + 1];
  const float kr = keypoints[n * 3 + 2];

  // Boxes exactly as reference (by2 uses kx — reference quirk, keep it)
  const float bx1 = fmaxf(kx - kr, 0.0f);
  const float by1 = fmaxf(ky - kr, 0.0f);
  const float bx2 = fminf(kx + kr, (float)NW);
  const float by2 = fminf(kx + kr, (float)NH);

  const float start_h = by1 - 0.5f;
  const float start_w = bx1 - 0.5f;
  const float bin_h = (by2 - by1) * (1.0f / (float)NP);
  const float bin_w = (bx2 - bx1) * (1.0f / (float)NP);
  const int gh = (int)ceilf(bin_h);       // == ceil(roi_h / P), 1..12
  const int gw = (int)ceilf(bin_w);       // 1..2
  const float ghf = (float)max(gh, 1);
  const float gwf = (float)max(gw, 1);
  const float inv_count = 1.0f / (float)max(gh * gw, 1);
  const float sub_h = bin_h / ghf;        // sub-sample spacing
  const float sub_w = bin_w / gwf;        // <= 1.0 (roi_w <= 32)

  const int i_lo = half << 3;             // first i-bin of this block

  // --- half-footprint extent (block-uniform; samples monotonic in i,gy) ---
  const float cy_min = start_h + (float)i_lo * bin_h + 0.5f * sub_h;
  const float cy_max = start_h + (float)(i_lo + 7) * bin_h + ((float)(gh - 1) + 0.5f) * sub_h;
  const float cx_min = start_w + 0.5f * sub_w;
  const float cx_max = start_w + 15.0f * bin_w + ((float)(gw - 1) + 0.5f) * sub_w;
  const int rmin = (int)floorf(fminf(fmaxf(cy_min, 0.0f), (float)(NH - 1)));
  const int rmax = min((int)floorf(fminf(fmaxf(cy_max, 0.0f), (float)(NH - 1))) + 1, NH - 1);
  const int cmin = (int)floorf(fminf(fmaxf(cx_min, 0.0f), (float)(NW - 1)));
  const int cmax = min((int)floorf(fminf(fmaxf(cx_max, 0.0f), (float)(NW - 1))) + 1, NW - 1);
  const int nrows = rmax - rmin + 1;          // <= 97
  const int cmin_al = cmin & ~3;              // 4-aligned for float4 loads
  const int nq = ((cmax - cmin_al) >> 2) + 1; // float4 groups per row, <= 10
  const int tot = nrows * nq;                 // <= 970
  const float inv_nq = 1.0f / (float)nq;

  const int img  = n / NO;                    // b*T + t
  const int bb   = img / NT;
  const int timg = img - bb * NT;
  const float* __restrict__ src0 =
      features + (size_t)((bb * NC + 0) * NT + timg) * (NH * NW);
  const size_t chs = (size_t)NT * NH * NW;    // channel stride in floats

  // --- register staging: 12 predicated float4 loads (4 slots x 3 channels),
  // addresses computed once, all loads independent and in flight together ---
  float4 a0, a1, a2, a3, b0, b1, b2, b3, c0, c1, c2, c3;
  int ro0, ro1, ro2, ro3;                     // slab-local LDS short offsets, -1 = skip
  int go0, go1, go2, go3;                     // global float offsets (row*NW+col)

#define ADDR(Q, RO, GO)                                                      \
  {                                                                          \
    const int e = tid + (Q << 8);                                            \
    if (e < tot) {                                                           \
      const int r  = (int)(((float)e + 0.5f) * inv_nq);                      \
      const int c4 = (e - r * nq) << 2;                                      \
      int gc = cmin_al + c4;                                                 \
      if (gc + 3 >= NW) gc = NW - 4;     /* clamp window: dup cols weight-0 */ \
      GO = (rmin + r) * NW + gc;                                             \
      RO = r * S_STRIDE + c4;                                                \
    } else { RO = -1; GO = 0; }                                              \
  }
  ADDR(0, ro0, go0) ADDR(1, ro1, go1) ADDR(2, ro2, go2) ADDR(3, ro3, go3)
#undef ADDR

  // (right-edge clamp correctness: identical argument to round 10 — shifted
  // duplicate cols land at LDS cols touched only by zero-weight taps.)

  // issue loads: 12 independent global_load_dwordx4, all in flight together
#define LD(V, GO, RO, CH)                                                    \
  if (RO >= 0) V = *reinterpret_cast<const float4*>(src0 + chs * CH + GO);
  LD(a0, go0, ro0, 0) LD(a1, go1, ro1, 0) LD(a2, go2, ro2, 0) LD(a3, go3, ro3, 0)
  LD(b0, go0, ro0, 1) LD(b1, go1, ro1, 1) LD(b2, go2, ro2, 1) LD(b3, go3, ro3, 1)
  LD(c0, go0, ro0, 2) LD(c1, go1, ro1, 2) LD(c2, go2, ro2, 2) LD(c3, go3, ro3, 2)
#undef LD

  // bf16-pack on the LDS write: 2 adjacent u32 per float4 (RO even -> aligned)
#define ST(V, RO, CH)                                                        \
  if (RO >= 0) {                                                             \
    unsigned* s = reinterpret_cast<unsigned*>(&S[CH * S_SLAB + RO]);         \
    s[0] = packbf(V.x, V.y); s[1] = packbf(V.z, V.w);                        \
  }
  ST(a0, ro0, 0) ST(a1, ro1, 0) ST(a2, ro2, 0) ST(a3, ro3, 0)
  ST(b0, ro0, 1) ST(b1, ro1, 1) ST(b2, ro2, 1) ST(b3, ro3, 1)
  ST(c0, ro0, 2) ST(c1, ro1, 2) ST(c2, ro2, 2) ST(c3, ro3, 2)
#undef ST

  // zero pad pair (cols nq*4, nq*4+1) per row per slab: window reads reach
  // them only with weight 0 — keep them finite, not stale bits.
  if (tid < nrows) {
    const int o = tid * S_STRIDE + (nq << 2);   // even short index
    *reinterpret_cast<unsigned*>(&S[o]) = 0u;
    *reinterpret_cast<unsigned*>(&S[S_SLAB + o]) = 0u;
    *reinterpret_cast<unsigned*>(&S[2 * S_SLAB + o]) = 0u;
  }

  __syncthreads();

  // --- sampling; thread pair (h=tid&1) splits gy; weights shared by 3 ch ---
  const int i = i_lo + (tid >> 5);        // this thread's output i-bin
  const int j = (tid >> 1) & 15;          // this thread's output j-bin
  const int h = tid & 1;                  // gy half: [h*6, h*6+6)

  // x-samples: gx=0 always valid; gx=1 weight-zeroed when gw==1.
  const float c0x = fminf(fmaxf(start_w + (float)j * bin_w + 0.5f * sub_w, 0.0f), (float)(NW - 1));
  const float c1x = fminf(fmaxf(start_w + (float)j * bin_w + 1.5f * sub_w, 0.0f), (float)(NW - 1));
  const int x00 = (int)floorf(c0x);
  const int x01 = (int)floorf(c1x);
  const float lx0 = c0x - (float)x00;
  const float hx0 = 1.0f - lx0;
  const float w1f = (gw > 1) ? 1.0f : 0.0f;
  const float lx1 = w1f * (c1x - (float)x01);
  const float hx1 = w1f * (1.0f - (c1x - (float)x01));
  const int xbg = x00 & ~1;               // even window base (global col)
  const int xb  = xbg - cmin_al;          // LDS short col of window (even, >=0)
  const int d0  = x00 - xbg;              // 0..1
  const int d1  = x01 - xbg;              // d0..d0+1 <= 2 (sub_w <= 1)

  // static 4-tap weights: tap k gets hx at k==d, lx at k==d+1, per gx
  const float xw0 = (d0 == 0 ? hx0 : 0.0f) + (d1 == 0 ? hx1 : 0.0f);
  const float xw1 = (d0 == 1 ? hx0 : 0.0f) + (d0 == 0 ? lx0 : 0.0f)
                  + (d1 == 1 ? hx1 : 0.0f) + (d1 == 0 ? lx1 : 0.0f);
  const float xw2 = (d0 == 1 ? lx0 : 0.0f)
                  + (d1 == 2 ? hx1 : 0.0f) + (d1 == 1 ? lx1 : 0.0f);
  const float xw3 = (d1 == 2 ? lx1 : 0.0f);

  float acc0 = 0.0f, acc1 = 0.0f, acc2 = 0.0f;
#pragma unroll
  for (int gg = 0; gg < 6; ++gg) {
    const int gy = h * 6 + gg;
    const float c = start_h + (float)i * bin_h + ((float)gy + 0.5f) * sub_h;
    const float cc = fminf(fmaxf(c, 0.0f), (float)(NH - 1));
    const int y0 = (int)floorf(cc);
    const float ly = cc - (float)y0;
    const bool vy = gy < gh;
    const float wl = vy ? ly : 0.0f;        // weight-zeroed instead of break
    const float wh = vy ? 1.0f - ly : 0.0f;
    const int r0  = min(y0 - rmin, nrows - 1);   // y0 >= rmin by monotonicity
    const int ry0 = r0 * S_STRIDE + xb;
    const int ry1 = min(r0 + 1, nrows - 1) * S_STRIDE + xb;
#pragma unroll
    for (int ch = 0; ch < 3; ++ch) {
      // 4-tap bf16 window per row: two adjacent u32 -> one ds_read2_b32
      const unsigned* sp0 = reinterpret_cast<const unsigned*>(&S[ch * S_SLAB + ry0]);
      const unsigned* sp1 = reinterpret_cast<const unsigned*>(&S[ch * S_SLAB + ry1]);
      const unsigned t0 = sp0[0], t1 = sp0[1];
      const unsigned u0 = sp1[0], u1 = sp1[1];
      const float dotT = xw0 * bflo(t0) + xw1 * bfhi(t0) + xw2 * bflo(t1) + xw3 * bfhi(t1);
      const float dotB = xw0 * bflo(u0) + xw1 * bfhi(u0) + xw2 * bflo(u1) + xw3 * bfhi(u1);
      const float d = wh * dotT + wl * dotB;
      if (ch == 0) acc0 += d; else if (ch == 1) acc1 += d; else acc2 += d;
    }
  }
  acc0 += __shfl_xor(acc0, 1);                // combine gy halves (lane pair)
  acc1 += __shfl_xor(acc1, 1);
  acc2 += __shfl_xor(acc2, 1);
  if (h == 0) {
    const size_t base = (size_t)n * NK + (i << 4) + j;
    pooled[base]               = f2bf(acc0 * inv_count);
    pooled[base + NP * NP]     = f2bf(acc1 * inv_count);
    pooled[base + 2 * NP * NP] = f2bf(acc2 * inv_count);
  }
}

// ---------------------------------------------------------------------------
// Kernel 2: bf16 MFMA GEMM  out[1600][768] = A[1600][768] . Bw[768][768]^T + b
// BM=BN=64, BK=64, grid 25x12=300 blocks, 4 waves (2x2), wave tile 32x32.
// Double-buffered LDS, 2-phase prefetch, XOR-swizzle via pre-swizzled source.
// (identical to round 4)
// ---------------------------------------------------------------------------
#define BM 64
#define BN 64
#define BK 64

static __device__ __forceinline__ void gld_lds16(const unsigned short* g,
                                                 unsigned short* l) {
  __builtin_amdgcn_global_load_lds(
      (const __attribute__((address_space(1))) unsigned int*)g,
      (__attribute__((address_space(3))) unsigned int*)l,
      16, 0, 0);
}

__global__ __launch_bounds__(256) void gemm_kernel(
    const unsigned short* __restrict__ A,    // [1600][768] bf16 (pooled)
    const unsigned short* __restrict__ Bw,   // [768][768]  bf16 (conv_w)
    const float* __restrict__ bias,          // [768]
    float* __restrict__ outp)                // [1600][768] f32
{
  __shared__ __align__(16) unsigned short As[2][BM * BK];   // 2 x 8 KB
  __shared__ __align__(16) unsigned short Bs[2][BM * BK];   // 2 x 8 KB

  const int tid = threadIdx.x;
  const int w = tid >> 6;           // wave 0..3
  const int l = tid & 63;           // lane
  const int bm = blockIdx.x * BM;
  const int bn = blockIdx.y * BN;

  const int wr = w >> 1, wc = w & 1;
  const int lr = l & 15;
  const int kh = l >> 4;            // 0..3

  const int rA0 = (wr << 5) + lr;   // A-frag rows (mi=0 / mi=1 = +16)
  const int rB0 = (wc << 5) + lr;   // B-frag rows (= C cols)

#define STAGE(buf, kk)                                                       \
  {                                                                          \
    _Pragma("unroll")                                                        \
    for (int q = 0; q < 2; ++q) {                                            \
      const int s   = (q << 8) + tid;                                        \
      const int row = s >> 3;                                                \
      const int c16 = (s & 7) ^ (row & 7);                                   \
      gld_lds16(A  + (size_t)(bm + row) * NK + (kk) + (c16 << 3),            \
                &As[buf][s << 3]);                                           \
      gld_lds16(Bw + (size_t)(bn + row) * NK + (kk) + (c16 << 3),            \
                &Bs[buf][s << 3]);                                           \
    }                                                                        \
  }

  f32x4 acc[2][2] = {};

  STAGE(0, 0)
  __syncthreads();                  // drains vmcnt(0)

  int cur = 0;
  for (int it = 0; it < NK / BK; ++it) {
    if (it + 1 < NK / BK) STAGE(cur ^ 1, (it + 1) * BK)   // overlap w/ compute

#pragma unroll
    for (int ks = 0; ks < 2; ++ks) {
      const int kq = (ks << 2) + kh;                      // k/8 quad index
      const bf16x8 a0 = *reinterpret_cast<const bf16x8*>(
          &As[cur][(rA0 << 6) + ((kq ^ (rA0 & 7)) << 3)]);
      const bf16x8 a1 = *reinterpret_cast<const bf16x8*>(
          &As[cur][((rA0 + 16) << 6) + ((kq ^ (rA0 & 7)) << 3)]);
      const bf16x8 b0 = *reinterpret_cast<const bf16x8*>(
          &Bs[cur][(rB0 << 6) + ((kq ^ (rB0 & 7)) << 3)]);
      const bf16x8 b1 = *reinterpret_cast<const bf16x8*>(
          &Bs[cur][((rB0 + 16) << 6) + ((kq ^ (rB0 & 7)) << 3)]);
      acc[0][0] = __builtin_amdgcn_mfma_f32_16x16x32_bf16(a0, b0, acc[0][0], 0, 0, 0);
      acc[0][1] = __builtin_amdgcn_mfma_f32_16x16x32_bf16(a0, b1, acc[0][1], 0, 0, 0);
      acc[1][0] = __builtin_amdgcn_mfma_f32_16x16x32_bf16(a1, b0, acc[1][0], 0, 0, 0);
      acc[1][1] = __builtin_amdgcn_mfma_f32_16x16x32_bf16(a1, b1, acc[1][1], 0, 0, 0);
    }

    __syncthreads();                // drains vmcnt (next tile landed) + LDS reuse
    cur ^= 1;
  }
#undef STAGE

  // Epilogue: C/D layout col = lane&15, row = (lane>>4)*4 + reg
#pragma unroll
  for (int ni = 0; ni < 2; ++ni) {
    const int col = bn + (wc << 5) + (ni << 4) + lr;
    const float bv = bias[col];
#pragma unroll
    for (int mi = 0; mi < 2; ++mi) {
      const int rbase = bm + (wr << 5) + (mi << 4) + (kh << 2);
#pragma unroll
      for (int q = 0; q < 4; ++q) {
        outp[(size_t)(rbase + q) * ND + col] = acc[mi][ni][q] + bv;
      }
    }
  }
}

extern "C" void kernel_launch(void* const* d_in, const int* in_sizes, int n_in,
                              void* d_out, int out_size, void* d_ws, size_t ws_size,
                              hipStream_t stream) {
  (void)in_sizes; (void)n_in; (void)out_size; (void)ws_size;
  const float* features  = (const float*)d_in[0];
  const float* keypoints = (const float*)d_in[1];
  const float* conv_w    = (const float*)d_in[2];
  const float* conv_b    = (const float*)d_in[3];
  float* outp = (float*)d_out;

  unsigned short* pooled = (unsigned short*)d_ws;                    // 2,457,600 B
  unsigned short* wbf    = (unsigned short*)((char*)d_ws + 2457600); // 1,179,648 B

  pool_convw_kernel<<<NSTREAM + NCVW + NHALF, 256, 0, stream>>>(
      features, keypoints, conv_w, pooled, wbf);

  dim3 grid(NKP / BM, ND / BN);   // 25 x 12 = 300
  gemm_kernel<<<grid, 256, 0, stream>>>(pooled, wbf, conv_b, outp);
}

// Round 13
// 33.833 us; speedup vs baseline: 1.2486x; 1.2486x over previous
//
#include <hip/hip_runtime.h>

// Problem constants (match reference)
#define NB 8
#define NT 8
#define NO 25
#define NC 3
#define NH 192
#define NW 640
#define NP 16
#define ND 768
#define NGH 12
#define NGW 2
#define NKP (NB*NT*NO)   // 1600 keypoints
#define NK (NC*NP*NP)    // 768 (GEMM K)
#define NHALF (NKP*2)    // 3200 pool blocks: (keypoint, row-half), 3 channels each
#define NCVW ((NK*ND)/(256*4))  // 576 convw blocks (float4 per thread)

#define S_STRIDE 42      // shorts per row (even: u32-aligned writes/reads)
#define S_ROWS 97        // half-footprint rows <= 97
#define S_SLAB (S_ROWS * S_STRIDE)   // shorts per channel slab (4074, even)

typedef __attribute__((ext_vector_type(4))) float  f32x4;
typedef __attribute__((ext_vector_type(8))) short  bf16x8;

static __device__ __forceinline__ unsigned short f2bf(float f) {
  union { float f; unsigned u; } x; x.f = f;
  unsigned r = x.u + 0x7FFFu + ((x.u >> 16) & 1u);   // round-to-nearest-even
  return (unsigned short)(r >> 16);
}
static __device__ __forceinline__ unsigned packbf(float lo, float hi) {
  return (unsigned)f2bf(lo) | ((unsigned)f2bf(hi) << 16);
}
static __device__ __forceinline__ float bflo(unsigned u) {
  union { unsigned x; float f; } v; v.x = u << 16; return v.f;
}
static __device__ __forceinline__ float bfhi(unsigned u) {
  union { unsigned x; float f; } v; v.x = u & 0xFFFF0000u; return v.f;
}

// ---------------------------------------------------------------------------
// Kernel 1 (fused): blocks [0,NCVW) convert conv_w f32->bf16;
// blocks [NCVW, NCVW+NHALF): ROI-align pooling, one block per
// (keypoint, row-half) covering ALL 3 CHANNELS.
// Footprint staged as BF16 (24.5 KB LDS -> 6 blocks/CU). The pool is bound
// by the scattered-gather line-fill rate (~1 TB/s measured, L3-resident);
// this configuration is the measured optimum (r11: 34.1 us).
// ---------------------------------------------------------------------------
__global__ __launch_bounds__(256) void pool_convw_kernel(
    const float* __restrict__ features,   // [B][C][T][H][W] f32
    const float* __restrict__ keypoints,  // [N][3] (kx, ky, kr)
    const float* __restrict__ conv_w,     // [768][768] f32
    unsigned short* __restrict__ pooled,  // [N][768] bf16
    unsigned short* __restrict__ wbf)     // [768][768] bf16
{
  __shared__ unsigned short S[3 * S_SLAB + 16];   // 24,476 B; +16 guard

  const int bid = blockIdx.x;
  const int tid = threadIdx.x;

  if (bid < NCVW) {                       // ---- conv_w convert path ----
    const int i = bid * 256 + tid;        // float4 index
    const float4 v = reinterpret_cast<const float4*>(conv_w)[i];
    ushort4 o;
    o.x = f2bf(v.x); o.y = f2bf(v.y); o.z = f2bf(v.z); o.w = f2bf(v.w);
    reinterpret_cast<ushort4*>(wbf)[i] = o;
    return;                               // no barrier on this path (block-uniform)
  }

  // ---- pooling path ----
  // XCD-chunked swizzle over 3200 (keypoint,half) blocks (3200 = 8*400).
  const int rb      = bid - NCVW;
  const int logical = (rb & 7) * (NHALF / 8) + (rb >> 3);
  const int n       = logical >> 1;
  const int half    = logical & 1;        // 0: i-bins [0,8), 1: [8,16)

  const float kx = keypoints[n * 3 + 0];
  const float ky = keypoints[n * 3 + 1];
  const float kr = keypoints[n * 3 + 2];

  // Boxes exactly as reference (by2 uses kx — reference quirk, keep it)
  const float bx1 = fmaxf(kx - kr, 0.0f);
  const float by1 = fmaxf(ky - kr, 0.0f);
  const float bx2 = fminf(kx + kr, (float)NW);
  const float by2 = fminf(kx + kr, (float)NH);

  const float start_h = by1 - 0.5f;
  const float start_w = bx1 - 0.5f;
  const float bin_h = (by2 - by1) * (1.0f / (float)NP);
  const float bin_w = (bx2 - bx1) * (1.0f / (float)NP);
  const int gh = (int)ceilf(bin_h);       // == ceil(roi_h / P), 1..12
  const int gw = (int)ceilf(bin_w);       // 1..2
  const float ghf = (float)max(gh, 1);
  const float gwf = (float)max(gw, 1);
  const float inv_count = 1.0f / (float)max(gh * gw, 1);
  const float sub_h = bin_h / ghf;        // sub-sample spacing
  const float sub_w = bin_w / gwf;        // <= 1.0 (roi_w <= 32)

  const int i_lo = half << 3;             // first i-bin of this block

  // --- half-footprint extent (block-uniform; samples monotonic in i,gy) ---
  const float cy_min = start_h + (float)i_lo * bin_h + 0.5f * sub_h;
  const float cy_max = start_h + (float)(i_lo + 7) * bin_h + ((float)(gh - 1) + 0.5f) * sub_h;
  const float cx_min = start_w + 0.5f * sub_w;
  const float cx_max = start_w + 15.0f * bin_w + ((float)(gw - 1) + 0.5f) * sub_w;
  const int rmin = (int)floorf(fminf(fmaxf(cy_min, 0.0f), (float)(NH - 1)));
  const int rmax = min((int)floorf(fminf(fmaxf(cy_max, 0.0f), (float)(NH - 1))) + 1, NH - 1);
  const int cmin = (int)floorf(fminf(fmaxf(cx_min, 0.0f), (float)(NW - 1)));
  const int cmax = min((int)floorf(fminf(fmaxf(cx_max, 0.0f), (float)(NW - 1))) + 1, NW - 1);
  const int nrows = rmax - rmin + 1;          // <= 97
  const int cmin_al = cmin & ~3;              // 4-aligned for float4 loads
  const int nq = ((cmax - cmin_al) >> 2) + 1; // float4 groups per row, <= 10
  const int tot = nrows * nq;                 // <= 970
  const float inv_nq = 1.0f / (float)nq;

  const int img  = n / NO;                    // b*T + t
  const int bb   = img / NT;
  const int timg = img - bb * NT;
  const float* __restrict__ src0 =
      features + (size_t)((bb * NC + 0) * NT + timg) * (NH * NW);
  const size_t chs = (size_t)NT * NH * NW;    // channel stride in floats

  // --- register staging: 12 predicated float4 loads (4 slots x 3 channels),
  // addresses computed once, all loads independent and in flight together ---
  float4 a0, a1, a2, a3, b0, b1, b2, b3, c0, c1, c2, c3;
  int ro0, ro1, ro2, ro3;                     // slab-local LDS short offsets, -1 = skip
  int go0, go1, go2, go3;                     // global float offsets (row*NW+col)

#define ADDR(Q, RO, GO)                                                      \
  {                                                                          \
    const int e = tid + (Q << 8);                                            \
    if (e < tot) {                                                           \
      const int r  = (int)(((float)e + 0.5f) * inv_nq);                      \
      const int c4 = (e - r * nq) << 2;                                      \
      int gc = cmin_al + c4;                                                 \
      if (gc + 3 >= NW) gc = NW - 4;     /* clamp window: dup cols weight-0 */ \
      GO = (rmin + r) * NW + gc;                                             \
      RO = r * S_STRIDE + c4;                                                \
    } else { RO = -1; GO = 0; }                                              \
  }
  ADDR(0, ro0, go0) ADDR(1, ro1, go1) ADDR(2, ro2, go2) ADDR(3, ro3, go3)
#undef ADDR

  // (right-edge clamp correctness: shifted duplicate cols land at LDS cols
  // touched only by zero-weight taps — same argument as round 10.)

  // issue loads: 12 independent global_load_dwordx4, all in flight together
#define LD(V, GO, RO, CH)                                                    \
  if (RO >= 0) V = *reinterpret_cast<const float4*>(src0 + chs * CH + GO);
  LD(a0, go0, ro0, 0) LD(a1, go1, ro1, 0) LD(a2, go2, ro2, 0) LD(a3, go3, ro3, 0)
  LD(b0, go0, ro0, 1) LD(b1, go1, ro1, 1) LD(b2, go2, ro2, 1) LD(b3, go3, ro3, 1)
  LD(c0, go0, ro0, 2) LD(c1, go1, ro1, 2) LD(c2, go2, ro2, 2) LD(c3, go3, ro3, 2)
#undef LD

  // bf16-pack on the LDS write: 2 adjacent u32 per float4 (RO even -> aligned)
#define ST(V, RO, CH)                                                        \
  if (RO >= 0) {                                                             \
    unsigned* s = reinterpret_cast<unsigned*>(&S[CH * S_SLAB + RO]);         \
    s[0] = packbf(V.x, V.y); s[1] = packbf(V.z, V.w);                        \
  }
  ST(a0, ro0, 0) ST(a1, ro1, 0) ST(a2, ro2, 0) ST(a3, ro3, 0)
  ST(b0, ro0, 1) ST(b1, ro1, 1) ST(b2, ro2, 1) ST(b3, ro3, 1)
  ST(c0, ro0, 2) ST(c1, ro1, 2) ST(c2, ro2, 2) ST(c3, ro3, 2)
#undef ST

  // zero pad pair (cols nq*4, nq*4+1) per row per slab: window reads reach
  // them only with weight 0 — keep them finite, not stale bits.
  if (tid < nrows) {
    const int o = tid * S_STRIDE + (nq << 2);   // even short index
    *reinterpret_cast<unsigned*>(&S[o]) = 0u;
    *reinterpret_cast<unsigned*>(&S[S_SLAB + o]) = 0u;
    *reinterpret_cast<unsigned*>(&S[2 * S_SLAB + o]) = 0u;
  }

  __syncthreads();

  // --- sampling; thread pair (h=tid&1) splits gy; weights shared by 3 ch ---
  const int i = i_lo + (tid >> 5);        // this thread's output i-bin
  const int j = (tid >> 1) & 15;          // this thread's output j-bin
  const int h = tid & 1;                  // gy half: [h*6, h*6+6)

  // x-samples: gx=0 always valid; gx=1 weight-zeroed when gw==1.
  const float c0x = fminf(fmaxf(start_w + (float)j * bin_w + 0.5f * sub_w, 0.0f), (float)(NW - 1));
  const float c1x = fminf(fmaxf(start_w + (float)j * bin_w + 1.5f * sub_w, 0.0f), (float)(NW - 1));
  const int x00 = (int)floorf(c0x);
  const int x01 = (int)floorf(c1x);
  const float lx0 = c0x - (float)x00;
  const float hx0 = 1.0f - lx0;
  const float w1f = (gw > 1) ? 1.0f : 0.0f;
  const float lx1 = w1f * (c1x - (float)x01);
  const float hx1 = w1f * (1.0f - (c1x - (float)x01));
  const int xbg = x00 & ~1;               // even window base (global col)
  const int xb  = xbg - cmin_al;          // LDS short col of window (even, >=0)
  const int d0  = x00 - xbg;              // 0..1
  const int d1  = x01 - xbg;              // d0..d0+1 <= 2 (sub_w <= 1)

  // static 4-tap weights: tap k gets hx at k==d, lx at k==d+1, per gx
  const float xw0 = (d0 == 0 ? hx0 : 0.0f) + (d1 == 0 ? hx1 : 0.0f);
  const float xw1 = (d0 == 1 ? hx0 : 0.0f) + (d0 == 0 ? lx0 : 0.0f)
                  + (d1 == 1 ? hx1 : 0.0f) + (d1 == 0 ? lx1 : 0.0f);
  const float xw2 = (d0 == 1 ? lx0 : 0.0f)
                  + (d1 == 2 ? hx1 : 0.0f) + (d1 == 1 ? lx1 : 0.0f);
  const float xw3 = (d1 == 2 ? lx1 : 0.0f);

  float acc0 = 0.0f, acc1 = 0.0f, acc2 = 0.0f;
#pragma unroll
  for (int gg = 0; gg < 6; ++gg) {
    const int gy = h * 6 + gg;
    const float c = start_h + (float)i * bin_h + ((float)gy + 0.5f) * sub_h;
    const float cc = fminf(fmaxf(c, 0.0f), (float)(NH - 1));
    const int y0 = (int)floorf(cc);
    const float ly = cc - (float)y0;
    const bool vy = gy < gh;
    const float wl = vy ? ly : 0.0f;        // weight-zeroed instead of break
    const float wh = vy ? 1.0f - ly : 0.0f;
    const int r0  = min(y0 - rmin, nrows - 1);   // y0 >= rmin by monotonicity
    const int ry0 = r0 * S_STRIDE + xb;
    const int ry1 = min(r0 + 1, nrows - 1) * S_STRIDE + xb;
#pragma unroll
    for (int ch = 0; ch < 3; ++ch) {
      // 4-tap bf16 window per row: two adjacent u32 -> one ds_read2_b32
      const unsigned* sp0 = reinterpret_cast<const unsigned*>(&S[ch * S_SLAB + ry0]);
      const unsigned* sp1 = reinterpret_cast<const unsigned*>(&S[ch * S_SLAB + ry1]);
      const unsigned t0 = sp0[0], t1 = sp0[1];
      const unsigned u0 = sp1[0], u1 = sp1[1];
      const float dotT = xw0 * bflo(t0) + xw1 * bfhi(t0) + xw2 * bflo(t1) + xw3 * bfhi(t1);
      const float dotB = xw0 * bflo(u0) + xw1 * bfhi(u0) + xw2 * bflo(u1) + xw3 * bfhi(u1);
      const float d = wh * dotT + wl * dotB;
      if (ch == 0) acc0 += d; else if (ch == 1) acc1 += d; else acc2 += d;
    }
  }
  acc0 += __shfl_xor(acc0, 1);                // combine gy halves (lane pair)
  acc1 += __shfl_xor(acc1, 1);
  acc2 += __shfl_xor(acc2, 1);
  if (h == 0) {
    const size_t base = (size_t)n * NK + (i << 4) + j;
    pooled[base]               = f2bf(acc0 * inv_count);
    pooled[base + NP * NP]     = f2bf(acc1 * inv_count);
    pooled[base + 2 * NP * NP] = f2bf(acc2 * inv_count);
  }
}

// ---------------------------------------------------------------------------
// Kernel 2: bf16 MFMA GEMM  out[1600][768] = A[1600][768] . Bw[768][768]^T + b
// BM=BN=64, BK=64, grid 25x12=300 blocks, 4 waves (2x2), wave tile 32x32.
// Double-buffered LDS, 2-phase prefetch, XOR-swizzle via pre-swizzled source.
// ---------------------------------------------------------------------------
#define BM 64
#define BN 64
#define BK 64

static __device__ __forceinline__ void gld_lds16(const unsigned short* g,
                                                 unsigned short* l) {
  __builtin_amdgcn_global_load_lds(
      (const __attribute__((address_space(1))) unsigned int*)g,
      (__attribute__((address_space(3))) unsigned int*)l,
      16, 0, 0);
}

__global__ __launch_bounds__(256) void gemm_kernel(
    const unsigned short* __restrict__ A,    // [1600][768] bf16 (pooled)
    const unsigned short* __restrict__ Bw,   // [768][768]  bf16 (conv_w)
    const float* __restrict__ bias,          // [768]
    float* __restrict__ outp)                // [1600][768] f32
{
  __shared__ __align__(16) unsigned short As[2][BM * BK];   // 2 x 8 KB
  __shared__ __align__(16) unsigned short Bs[2][BM * BK];   // 2 x 8 KB

  const int tid = threadIdx.x;
  const int w = tid >> 6;           // wave 0..3
  const int l = tid & 63;           // lane
  const int bm = blockIdx.x * BM;
  const int bn = blockIdx.y * BN;

  const int wr = w >> 1, wc = w & 1;
  const int lr = l & 15;
  const int kh = l >> 4;            // 0..3

  const int rA0 = (wr << 5) + lr;   // A-frag rows (mi=0 / mi=1 = +16)
  const int rB0 = (wc << 5) + lr;   // B-frag rows (= C cols)

#define STAGE(buf, kk)                                                       \
  {                                                                          \
    _Pragma("unroll")                                                        \
    for (int q = 0; q < 2; ++q) {                                            \
      const int s   = (q << 8) + tid;                                        \
      const int row = s >> 3;                                                \
      const int c16 = (s & 7) ^ (row & 7);                                   \
      gld_lds16(A  + (size_t)(bm + row) * NK + (kk) + (c16 << 3),            \
                &As[buf][s << 3]);                                           \
      gld_lds16(Bw + (size_t)(bn + row) * NK + (kk) + (c16 << 3),            \
                &Bs[buf][s << 3]);                                           \
    }                                                                        \
  }

  f32x4 acc[2][2] = {};

  STAGE(0, 0)
  __syncthreads();                  // drains vmcnt(0)

  int cur = 0;
  for (int it = 0; it < NK / BK; ++it) {
    if (it + 1 < NK / BK) STAGE(cur ^ 1, (it + 1) * BK)   // overlap w/ compute

#pragma unroll
    for (int ks = 0; ks < 2; ++ks) {
      const int kq = (ks << 2) + kh;                      // k/8 quad index
      const bf16x8 a0 = *reinterpret_cast<const bf16x8*>(
          &As[cur][(rA0 << 6) + ((kq ^ (rA0 & 7)) << 3)]);
      const bf16x8 a1 = *reinterpret_cast<const bf16x8*>(
          &As[cur][((rA0 + 16) << 6) + ((kq ^ (rA0 & 7)) << 3)]);
      const bf16x8 b0 = *reinterpret_cast<const bf16x8*>(
          &Bs[cur][(rB0 << 6) + ((kq ^ (rB0 & 7)) << 3)]);
      const bf16x8 b1 = *reinterpret_cast<const bf16x8*>(
          &Bs[cur][((rB0 + 16) << 6) + ((kq ^ (rB0 & 7)) << 3)]);
      acc[0][0] = __builtin_amdgcn_mfma_f32_16x16x32_bf16(a0, b0, acc[0][0], 0, 0, 0);
      acc[0][1] = __builtin_amdgcn_mfma_f32_16x16x32_bf16(a0, b1, acc[0][1], 0, 0, 0);
      acc[1][0] = __builtin_amdgcn_mfma_f32_16x16x32_bf16(a1, b0, acc[1][0], 0, 0, 0);
      acc[1][1] = __builtin_amdgcn_mfma_f32_16x16x32_bf16(a1, b1, acc[1][1], 0, 0, 0);
    }

    __syncthreads();                // drains vmcnt (next tile landed) + LDS reuse
    cur ^= 1;
  }
#undef STAGE

  // Epilogue: C/D layout col = lane&15, row = (lane>>4)*4 + reg
#pragma unroll
  for (int ni = 0; ni < 2; ++ni) {
    const int col = bn + (wc << 5) + (ni << 4) + lr;
    const float bv = bias[col];
#pragma unroll
    for (int mi = 0; mi < 2; ++mi) {
      const int rbase = bm + (wr << 5) + (mi << 4) + (kh << 2);
#pragma unroll
      for (int q = 0; q < 4; ++q) {
        outp[(size_t)(rbase + q) * ND + col] = acc[mi][ni][q] + bv;
      }
    }
  }
}

extern "C" void kernel_launch(void* const* d_in, const int* in_sizes, int n_in,
                              void* d_out, int out_size, void* d_ws, size_t ws_size,
                              hipStream_t stream) {
  (void)in_sizes; (void)n_in; (void)out_size; (void)ws_size;
  const float* features  = (const float*)d_in[0];
  const float* keypoints = (const float*)d_in[1];
  const float* conv_w    = (const float*)d_in[2];
  const float* conv_b    = (const float*)d_in[3];
  float* outp = (float*)d_out;

  unsigned short* pooled = (unsigned short*)d_ws;                    // 2,457,600 B
  unsigned short* wbf    = (unsigned short*)((char*)d_ws + 2457600); // 1,179,648 B

  pool_convw_kernel<<<NCVW + NHALF, 256, 0, stream>>>(features, keypoints,
                                                      conv_w, pooled, wbf);

  dim3 grid(NKP / BM, ND / BN);   // 25 x 12 = 300
  gemm_kernel<<<grid, 256, 0, stream>>>(pooled, wbf, conv_b, outp);
}